// Round 19
// baseline (46.299 us; speedup 1.0000x reference)
//
#include <hip/hip_runtime.h>

// Depthwise 7x7 'same' conv, fp32 in/out. B=16, C=256, H=W=64.
// Untested cell of the design space: R13's small tile (lane = 4w x 4h,
// 16 acc, wave = quarter-plane, 16384 waves) + R14's distance-5
// dataflow load pipeline + lb(256,4) (cap 128, 4 waves/SIMD).
// Live set ~110 VGPR (16 acc + 5 slots x 12 + ~30 working) fits 128 —
// R16's spill needed ~145. Goal: raise duty cycle (R14: 42%) via
// 4 waves/SIMD TLP on top of in-wave MLP; both proven individually
// insufficient, never combined.

typedef _Float16 v2h __attribute__((ext_vector_type(2)));

static __device__ __forceinline__ v2h pack2(float a, float b) {
    return __builtin_bit_cast(v2h, __builtin_amdgcn_cvt_pkrtz(a, b));
}

__global__ __launch_bounds__(256, 4)
void dwconv7x7_q5(const float* __restrict__ x,
                  const float* __restrict__ weight,
                  const float* __restrict__ bias,
                  float* __restrict__ out) {
    const int tid  = threadIdx.x;
    const int lane = tid & 63;
    const int wid  = tid >> 6;
    const int gw   = blockIdx.x * 4 + wid;   // 0..16383
    const int plane = gw >> 2;               // b*256 + c
    const int quart = gw & 3;                // 16-row band
    const int c = __builtin_amdgcn_readfirstlane(plane & 255);

    // ---- per-channel weights (uniform): half2 pairs in SGPRs ----
    const float* wp = weight + c * 49;
    float wk[49];
#pragma unroll
    for (int k = 0; k < 49; ++k) wk[k] = wp[k];
    const float bv = bias[c];

    v2h  W[7][3];     // taps (0,1),(2,3),(4,5) per kernel row
    float w6[7];      // tap 6 scalar
#pragma unroll
    for (int kr = 0; kr < 7; ++kr) {
#pragma unroll
        for (int t = 0; t < 3; ++t) {
            v2h p = pack2(wk[kr * 7 + 2 * t], wk[kr * 7 + 2 * t + 1]);
            int b = __builtin_amdgcn_readfirstlane(__builtin_bit_cast(int, p));
            W[kr][t] = __builtin_bit_cast(v2h, b);
        }
        w6[kr] = wk[kr * 7 + 6];
    }

    const int tx = lane & 15;             // 16 tiles across width
    const int sy = lane >> 4;             // 4 strips per quarter
    const int wb = tx * 4;                // output col base
    const int hb = quart * 16 + sy * 4;   // output row base

    const float* xp = x + (size_t)plane * 4096;
    const int offm = (tx > 0)  ? (wb - 4) : wb;   // clamped aligned left
    const int offp = (tx < 15) ? (wb + 4) : wb;   // clamped aligned right

    float acc[4][4];
#pragma unroll
    for (int i = 0; i < 4; ++i)
#pragma unroll
        for (int j = 0; j < 4; ++j) acc[i][j] = 0.f;

    // load pipeline: L[j] holds row (hb-3+j)'s 3 dwordx4; 10 row-steps.
    float4 L[10][3];

#define ISSUE(J) do {                                              \
        const int rr_ = min(max(hb - 3 + (J), 0), 63);             \
        const float* rowp_ = xp + rr_ * 64;                        \
        L[J][0] = *reinterpret_cast<const float4*>(rowp_ + offm);  \
        L[J][1] = *reinterpret_cast<const float4*>(rowp_ + wb);    \
        L[J][2] = *reinterpret_cast<const float4*>(rowp_ + offp);  \
    } while (0)

    // prologue: rows 0..4 in flight (15 loads)
#pragma unroll
    for (int j = 0; j < 5; ++j) ISSUE(j);

#pragma unroll
    for (int j = 0; j < 10; ++j) {
        const int r = hb - 3 + j;
        const bool mrow = (r >= 0) && (r < 64);
        const bool mm = mrow && (tx > 0);
        const bool mp = mrow && (tx < 15);

        // f[i] = x[r][wb-3+i], i = 0..9 (masked to zero outside)
        float f[10];
        f[0] = mm   ? L[j][0].y : 0.f;
        f[1] = mm   ? L[j][0].z : 0.f;
        f[2] = mm   ? L[j][0].w : 0.f;
        f[3] = mrow ? L[j][1].x : 0.f;
        f[4] = mrow ? L[j][1].y : 0.f;
        f[5] = mrow ? L[j][1].z : 0.f;
        f[6] = mrow ? L[j][1].w : 0.f;
        f[7] = mp   ? L[j][2].x : 0.f;
        f[8] = mp   ? L[j][2].y : 0.f;
        f[9] = mp   ? L[j][2].z : 0.f;

        // keep the pipeline 5 ahead
        if (j + 5 < 10) ISSUE(j + 5);

        // sliding half2 pairs: pk[t] = (f[t], f[t+1])
        v2h pk[8];
#pragma unroll
        for (int t = 0; t < 8; ++t) pk[t] = pack2(f[t], f[t + 1]);

        // output row oi (kr = j - oi), col wb+jj: taps -> f[jj+kc]
#pragma unroll
        for (int oi = 0; oi < 4; ++oi) {
            const int kr = j - oi;
            if (kr >= 0 && kr < 7) {
#pragma unroll
                for (int jj = 0; jj < 4; ++jj) {
                    float a = fmaf(f[jj + 6], w6[kr], acc[oi][jj]);
                    a = __builtin_amdgcn_fdot2(pk[jj + 4], W[kr][2], a, false);
                    a = __builtin_amdgcn_fdot2(pk[jj + 2], W[kr][1], a, false);
                    a = __builtin_amdgcn_fdot2(pk[jj],     W[kr][0], a, false);
                    acc[oi][jj] = a;
                }
            }
        }
    }
#undef ISSUE

    // ---- write 4 rows x float4, plus bias ----
    float* op = out + (size_t)plane * 4096 + (size_t)hb * 64 + wb;
#pragma unroll
    for (int oi = 0; oi < 4; ++oi) {
        float4 v;
        v.x = acc[oi][0] + bv;
        v.y = acc[oi][1] + bv;
        v.z = acc[oi][2] + bv;
        v.w = acc[oi][3] + bv;
        *reinterpret_cast<float4*>(op + oi * 64) = v;
    }
}

extern "C" void kernel_launch(void* const* d_in, const int* in_sizes, int n_in,
                              void* d_out, int out_size, void* d_ws, size_t ws_size,
                              hipStream_t stream) {
    const float* x      = (const float*)d_in[0];
    const float* weight = (const float*)d_in[1];
    const float* bias   = (const float*)d_in[2];
    float* out          = (float*)d_out;
    (void)in_sizes; (void)n_in; (void)out_size; (void)d_ws; (void)ws_size;

    // 16384 waves = 4096 blocks x 256 threads (4 waves/block)
    dim3 grid(4096);
    dim3 block(256);
    dwconv7x7_q5<<<grid, block, 0, stream>>>(x, weight, bias, out);
}

// Round 20
// 39.755 us; speedup vs baseline: 1.1646x; 1.1646x over previous
//
#include <hip/hip_runtime.h>

// Depthwise 7x7 'same' conv, fp32 in/out. B=16, C=256, H=W=64.
// Untested combination: R8's 8-wide x 8-high tile (one wave per plane,
// 4096 waves; 4 aligned dwordx4 feed 8 outputs -> half of R14's VMEM
// instrs and half the per-output extraction cost) + R14's distance-5
// dataflow load pipeline + dot2 inner product. lb(256,2) (cap 256 —
// R8 allocated 124 spill-free here; pipeline adds ~80 -> ~200 live).
// Spill tripwire: VGPR<=80 with FETCH/WRITE ballooned (R16/R19 mode).

typedef _Float16 v2h __attribute__((ext_vector_type(2)));

static __device__ __forceinline__ v2h pack2(float a, float b) {
    return __builtin_bit_cast(v2h, __builtin_amdgcn_cvt_pkrtz(a, b));
}

__global__ __launch_bounds__(256, 2)
void dwconv7x7_w8p(const float* __restrict__ x,
                   const float* __restrict__ weight,
                   const float* __restrict__ bias,
                   float* __restrict__ out) {
    const int tid  = threadIdx.x;
    const int lane = tid & 63;
    const int wid  = tid >> 6;
    const int plane = blockIdx.x * 4 + wid;  // 0..4095 = b*256 + c
    const int c = __builtin_amdgcn_readfirstlane(plane & 255);

    // ---- per-channel weights (uniform): half2 pairs in SGPRs ----
    const float* wp = weight + c * 49;
    float wk[49];
#pragma unroll
    for (int k = 0; k < 49; ++k) wk[k] = wp[k];
    const float bv = bias[c];

    v2h  W[7][3];     // taps (0,1),(2,3),(4,5) per kernel row
    float w6[7];      // tap 6 scalar
#pragma unroll
    for (int kr = 0; kr < 7; ++kr) {
#pragma unroll
        for (int t = 0; t < 3; ++t) {
            v2h p = pack2(wk[kr * 7 + 2 * t], wk[kr * 7 + 2 * t + 1]);
            int b = __builtin_amdgcn_readfirstlane(__builtin_bit_cast(int, p));
            W[kr][t] = __builtin_bit_cast(v2h, b);
        }
        w6[kr] = wk[kr * 7 + 6];
    }

    const int tx = lane & 7;          // 8 tiles across width
    const int sy = lane >> 3;         // 8 strips down height
    const int wb = tx * 8;            // output col base
    const int hb = sy * 8;            // output row base

    const float* xp = x + (size_t)plane * 4096;
    const int offm = (tx > 0) ? (wb - 4) : wb;   // clamped aligned left
    const int offp = (tx < 7) ? (wb + 8) : wb;   // clamped aligned right

    float acc[8][8];
#pragma unroll
    for (int i = 0; i < 8; ++i)
#pragma unroll
        for (int j = 0; j < 8; ++j) acc[i][j] = 0.f;

    // distance-5 load pipeline: L[j] = row (hb-3+j)'s 4 dwordx4.
    float4 L[14][4];

#define ISSUE(J) do {                                                 \
        const int rr_ = min(max(hb - 3 + (J), 0), 63);                \
        const float* rowp_ = xp + rr_ * 64;                           \
        L[J][0] = *reinterpret_cast<const float4*>(rowp_ + offm);     \
        L[J][1] = *reinterpret_cast<const float4*>(rowp_ + wb);       \
        L[J][2] = *reinterpret_cast<const float4*>(rowp_ + wb + 4);   \
        L[J][3] = *reinterpret_cast<const float4*>(rowp_ + offp);     \
    } while (0)

    // prologue: rows 0..4 in flight (20 loads)
#pragma unroll
    for (int j = 0; j < 5; ++j) ISSUE(j);

#pragma unroll
    for (int j = 0; j < 14; ++j) {
        const int r = hb - 3 + j;
        const bool mrow = (r >= 0) && (r < 64);
        const bool mm = mrow && (tx > 0);
        const bool mp = mrow && (tx < 7);

        // f[i] = x[r][wb-4+i], i = 0..15 (masked to zero outside)
        float f[16];
        f[0]  = mm   ? L[j][0].x : 0.f;
        f[1]  = mm   ? L[j][0].y : 0.f;
        f[2]  = mm   ? L[j][0].z : 0.f;
        f[3]  = mm   ? L[j][0].w : 0.f;
        f[4]  = mrow ? L[j][1].x : 0.f;
        f[5]  = mrow ? L[j][1].y : 0.f;
        f[6]  = mrow ? L[j][1].z : 0.f;
        f[7]  = mrow ? L[j][1].w : 0.f;
        f[8]  = mrow ? L[j][2].x : 0.f;
        f[9]  = mrow ? L[j][2].y : 0.f;
        f[10] = mrow ? L[j][2].z : 0.f;
        f[11] = mrow ? L[j][2].w : 0.f;
        f[12] = mp   ? L[j][3].x : 0.f;
        f[13] = mp   ? L[j][3].y : 0.f;
        f[14] = mp   ? L[j][3].z : 0.f;
        f[15] = mp   ? L[j][3].w : 0.f;

        // keep the pipeline 5 ahead
        if (j + 5 < 14) ISSUE(j + 5);

        // sliding half2 pairs pk[t] = (f[t], f[t+1]), t = 1..12 used
        v2h pk[13];
#pragma unroll
        for (int t = 1; t <= 12; ++t) pk[t] = pack2(f[t], f[t + 1]);

        // output col wb+jj, kernel row kr = j - oi:
        // taps kc -> f[1+jj+kc]; pairs pk[1+jj], pk[3+jj], pk[5+jj];
        // tap 6 scalar f[7+jj].
#pragma unroll
        for (int oi = 0; oi < 8; ++oi) {
            const int kr = j - oi;
            if (kr >= 0 && kr < 7) {
#pragma unroll
                for (int jj = 0; jj < 8; ++jj) {
                    float a = fmaf(f[7 + jj], w6[kr], acc[oi][jj]);
                    a = __builtin_amdgcn_fdot2(pk[5 + jj], W[kr][2], a, false);
                    a = __builtin_amdgcn_fdot2(pk[3 + jj], W[kr][1], a, false);
                    a = __builtin_amdgcn_fdot2(pk[1 + jj], W[kr][0], a, false);
                    acc[oi][jj] = a;
                }
            }
        }
    }
#undef ISSUE

    // ---- write 8 rows x 2 float4 each, plus bias ----
    float* op = out + (size_t)plane * 4096 + (size_t)hb * 64 + wb;
#pragma unroll
    for (int oi = 0; oi < 8; ++oi) {
        float4 v0, v1;
        v0.x = acc[oi][0] + bv;
        v0.y = acc[oi][1] + bv;
        v0.z = acc[oi][2] + bv;
        v0.w = acc[oi][3] + bv;
        v1.x = acc[oi][4] + bv;
        v1.y = acc[oi][5] + bv;
        v1.z = acc[oi][6] + bv;
        v1.w = acc[oi][7] + bv;
        *reinterpret_cast<float4*>(op + oi * 64)     = v0;
        *reinterpret_cast<float4*>(op + oi * 64 + 4) = v1;
    }
}

extern "C" void kernel_launch(void* const* d_in, const int* in_sizes, int n_in,
                              void* d_out, int out_size, void* d_ws, size_t ws_size,
                              hipStream_t stream) {
    const float* x      = (const float*)d_in[0];
    const float* weight = (const float*)d_in[1];
    const float* bias   = (const float*)d_in[2];
    float* out          = (float*)d_out;
    (void)in_sizes; (void)n_in; (void)out_size; (void)d_ws; (void)ws_size;

    // 4096 waves = 1024 blocks x 256 threads (4 waves/block, 1 wave/plane)
    dim3 grid(1024);
    dim3 block(256);
    dwconv7x7_w8p<<<grid, block, 0, stream>>>(x, weight, bias, out);
}

// Round 21
// 31.562 us; speedup vs baseline: 1.4669x; 1.2596x over previous
//
#include <hip/hip_runtime.h>

// Depthwise 7x7 'same' conv, fp32 in/out. B=16, C=256, H=W=64.
// Block = one (b,c) plane (4096 blocks x 256 thr). The plane (16 KB) is
// staged into LDS via 16x global_load_lds width=16 (async DMA, ZERO VGPR
// cost -> outstanding loads no longer fight the register allocator,
// which killed R16/R19/R20). LDS layout is LINEAR [64][64] (gload_lds
// requires contiguous dest = wave-uniform base + lane*16).
// Compute = R13's verified 4x4-tile dot2 path reading ds_read_b128.
// Bank math: quad = (tx + delta) mod 8 -> uniform 8 lanes/quad (minimum).
// ~60 VGPR -> 8 blocks/CU resident; one block's stage hides under 7
// others' compute.

typedef _Float16 v2h __attribute__((ext_vector_type(2)));

static __device__ __forceinline__ v2h pack2(float a, float b) {
    return __builtin_bit_cast(v2h, __builtin_amdgcn_cvt_pkrtz(a, b));
}

__global__ void dwconv7x7_glds(const float* __restrict__ x,
                               const float* __restrict__ weight,
                               const float* __restrict__ bias,
                               float* __restrict__ out) {
    __shared__ float lds[64 * 64];

    const int tid   = threadIdx.x;     // 0..255
    const int lane  = tid & 63;
    const int wid   = tid >> 6;        // wave 0..3
    const int plane = blockIdx.x;      // b*256 + c
    const int c     = plane & 255;     // block-uniform

    const float* xp = x + (size_t)plane * 4096;

    // ---- stage the whole plane into LDS (VGPR-free async DMA) ----
    // wave w stages chunks 4w..4w+3; chunk = 1 KB = 4 plane rows.
    // HW writes lane l's 16 B at lds_base + l*16; global src is per-lane.
    {
        auto* gsrc  = (const __attribute__((address_space(1))) float*)xp;
        auto* lbase = (__attribute__((address_space(3))) float*)lds;
#pragma unroll
        for (int k = 0; k < 4; ++k) {
            const int chunk = wid * 4 + k;           // wave-uniform
            __builtin_amdgcn_global_load_lds(
                (const __attribute__((address_space(1))) void*)
                    (gsrc + chunk * 256 + lane * 4),
                (__attribute__((address_space(3))) void*)(lbase + chunk * 256),
                16, 0, 0);
        }
    }

    // ---- weights while the DMA is in flight (uniform -> SGPRs) ----
    const float* wp = weight + c * 49;
    float wk[49];
#pragma unroll
    for (int k = 0; k < 49; ++k) wk[k] = wp[k];
    const float bv = bias[c];

    v2h  W[7][3];     // taps (0,1),(2,3),(4,5) per kernel row
    float w6[7];      // tap 6 scalar
#pragma unroll
    for (int kr = 0; kr < 7; ++kr) {
#pragma unroll
        for (int t = 0; t < 3; ++t) {
            v2h p = pack2(wk[kr * 7 + 2 * t], wk[kr * 7 + 2 * t + 1]);
            int b = __builtin_amdgcn_readfirstlane(__builtin_bit_cast(int, p));
            W[kr][t] = __builtin_bit_cast(v2h, b);
        }
        w6[kr] = wk[kr * 7 + 6];
    }

    // drain the DMA, then publish LDS to all waves
    asm volatile("s_waitcnt vmcnt(0)" ::: "memory");
    __syncthreads();

    // ---- compute: lane = 4w x 4h tile; wave = 16-row band ----
    const int tx = lane & 15;            // 16 tiles across width
    const int sy = lane >> 4;            // 4 strips per wave
    const int wb = tx * 4;               // output col base
    const int hb = wid * 16 + sy * 4;    // output row base

    const int offm = (tx > 0)  ? (wb - 4) : wb;   // clamped aligned left
    const int offp = (tx < 15) ? (wb + 4) : wb;   // clamped aligned right

    float acc[4][4];
#pragma unroll
    for (int i = 0; i < 4; ++i)
#pragma unroll
        for (int j = 0; j < 4; ++j) acc[i][j] = 0.f;

    // Stream input rows hb-3 .. hb+6 (10 steps) from LDS.
#pragma unroll
    for (int j = 0; j < 10; ++j) {
        const int r  = hb - 3 + j;
        const int rc = min(max(r, 0), 63);
        const float* rp = &lds[rc * 64];
        const bool mrow = (r >= 0) && (r < 64);
        const bool mm = mrow && (tx > 0);
        const bool mp = mrow && (tx < 15);

        float4 qm = *reinterpret_cast<const float4*>(rp + offm);
        float4 q0 = *reinterpret_cast<const float4*>(rp + wb);
        float4 qp = *reinterpret_cast<const float4*>(rp + offp);

        // f[i] = x[r][wb-3+i], i = 0..9 (masked to zero outside)
        float f[10];
        f[0] = mm   ? qm.y : 0.f;
        f[1] = mm   ? qm.z : 0.f;
        f[2] = mm   ? qm.w : 0.f;
        f[3] = mrow ? q0.x : 0.f;
        f[4] = mrow ? q0.y : 0.f;
        f[5] = mrow ? q0.z : 0.f;
        f[6] = mrow ? q0.w : 0.f;
        f[7] = mp   ? qp.x : 0.f;
        f[8] = mp   ? qp.y : 0.f;
        f[9] = mp   ? qp.z : 0.f;

        // sliding half2 pairs: pk[t] = (f[t], f[t+1])
        v2h pk[8];
#pragma unroll
        for (int t = 0; t < 8; ++t) pk[t] = pack2(f[t], f[t + 1]);

        // output row oi (kr = j - oi), col wb+jj: taps -> f[jj+kc]
#pragma unroll
        for (int oi = 0; oi < 4; ++oi) {
            const int kr = j - oi;
            if (kr >= 0 && kr < 7) {
#pragma unroll
                for (int jj = 0; jj < 4; ++jj) {
                    float a = fmaf(f[jj + 6], w6[kr], acc[oi][jj]);
                    a = __builtin_amdgcn_fdot2(pk[jj + 4], W[kr][2], a, false);
                    a = __builtin_amdgcn_fdot2(pk[jj + 2], W[kr][1], a, false);
                    a = __builtin_amdgcn_fdot2(pk[jj],     W[kr][0], a, false);
                    acc[oi][jj] = a;
                }
            }
        }
    }

    // ---- write 4 rows x float4, plus bias ----
    float* op = out + (size_t)plane * 4096 + (size_t)hb * 64 + wb;
#pragma unroll
    for (int oi = 0; oi < 4; ++oi) {
        float4 v;
        v.x = acc[oi][0] + bv;
        v.y = acc[oi][1] + bv;
        v.z = acc[oi][2] + bv;
        v.w = acc[oi][3] + bv;
        *reinterpret_cast<float4*>(op + oi * 64) = v;
    }
}

extern "C" void kernel_launch(void* const* d_in, const int* in_sizes, int n_in,
                              void* d_out, int out_size, void* d_ws, size_t ws_size,
                              hipStream_t stream) {
    const float* x      = (const float*)d_in[0];
    const float* weight = (const float*)d_in[1];
    const float* bias   = (const float*)d_in[2];
    float* out          = (float*)d_out;
    (void)in_sizes; (void)n_in; (void)out_size; (void)d_ws; (void)ws_size;

    dim3 grid(4096);   // one block per (b, c) plane
    dim3 block(256);
    dwconv7x7_glds<<<grid, block, 0, stream>>>(x, weight, bias, out);
}